// Round 12
// baseline (26108.447 us; speedup 1.0000x reference)
//
#include <hip/hip_runtime.h>
#include <math.h>

// PhysicsLSGStep: bitwise-faithful f32 replication of the numpy reference
// (model H11, PASSED R9-R11 @ absmax 0.484375).
// R12: edge kernels row-per-thread with 8-edge batched indirection (list ->
// inv/idx -> row, one waitcnt round per stage per batch) — accumulation order
// per (node,feat) is UNCHANGED. k_dot grid = exact leaf count (host-computed).
// - np.add.at scatters: per-(node,feat) sequential f32, edge order (CSR).
// - np.sum: acc init from FIRST element + numpy pairwise tree over n-1
//   (8-acc base blocks <=128, n2 -= n2%8 splits), replayed exactly.
// - elementwise: f32 __f*_rn, no FMA contraction.

#define F 8
#define CG_ITERS 30
#define LEAF_T 4096

#define S_RS    0
#define S_ALPHA 1
#define S_BETA  2
#define S_DONE  3
#define S_DONE2 4

__device__ __forceinline__ float dt_eff_of(const float* dtp) {
    return fminf(fmaxf(dtp[0], 0.02f), 2.0f);
}

// ---------- numpy pairwise sum base block (sum of a[i]*b[i], n<=128) ----------

__device__ float pw_base(const float* a, const float* b, int n) {
    if (n < 8) {
        float res = 0.f;
        for (int i = 0; i < n; ++i) res = __fadd_rn(res, __fmul_rn(a[i], b[i]));
        return res;
    }
    float r0 = __fmul_rn(a[0], b[0]);
    float r1 = __fmul_rn(a[1], b[1]);
    float r2 = __fmul_rn(a[2], b[2]);
    float r3 = __fmul_rn(a[3], b[3]);
    float r4 = __fmul_rn(a[4], b[4]);
    float r5 = __fmul_rn(a[5], b[5]);
    float r6 = __fmul_rn(a[6], b[6]);
    float r7 = __fmul_rn(a[7], b[7]);
    int i = 8;
    int lim = n - (n & 7);
    for (; i < lim; i += 8) {
        r0 = __fadd_rn(r0, __fmul_rn(a[i + 0], b[i + 0]));
        r1 = __fadd_rn(r1, __fmul_rn(a[i + 1], b[i + 1]));
        r2 = __fadd_rn(r2, __fmul_rn(a[i + 2], b[i + 2]));
        r3 = __fadd_rn(r3, __fmul_rn(a[i + 3], b[i + 3]));
        r4 = __fadd_rn(r4, __fmul_rn(a[i + 4], b[i + 4]));
        r5 = __fadd_rn(r5, __fmul_rn(a[i + 5], b[i + 5]));
        r6 = __fadd_rn(r6, __fmul_rn(a[i + 6], b[i + 6]));
        r7 = __fadd_rn(r7, __fmul_rn(a[i + 7], b[i + 7]));
    }
    float res = __fadd_rn(__fadd_rn(__fadd_rn(r0, r1), __fadd_rn(r2, r3)),
                          __fadd_rn(__fadd_rn(r4, r5), __fadd_rn(r6, r7)));
    for (; i < n; ++i) res = __fadd_rn(res, __fmul_rn(a[i], b[i]));
    return res;
}

// leaf decomposition of virtual [0, n) (n = NF-1; physical offset +1).
__global__ void k_build_leaves(int n, int* leafOff, int* leafN, int* nLeaf) {
    __shared__ int spOff[40], spN[40];
    if (threadIdx.x != 0 || blockIdx.x != 0) return;
    int sp = 0;
    spOff[0] = 0; spN[0] = n;
    int cnt = 0;
    while (sp >= 0) {
        int off = spOff[sp], nn = spN[sp]; sp--;
        if (nn <= LEAF_T) {
            if (cnt < 2048) { leafOff[cnt] = off; leafN[cnt] = nn; }
            cnt++;
        } else {
            int n2 = nn / 2; n2 -= (n2 & 7);
            spOff[++sp] = off + n2; spN[sp] = nn - n2;  // right (popped second)
            spOff[++sp] = off;      spN[sp] = n2;       // left  (popped first)
        }
    }
    *nLeaf = cnt;
}

// full dot: one wave per leaf + last-block upper-tree combine + scalar update.
// All tree-walk stacks in LDS. blockDim = 64. n = NF-1 (virtual), phys +1.
__global__ void k_dot(const float* __restrict__ a, const float* __restrict__ b,
                      const int* __restrict__ leafOff, const int* __restrict__ leafN,
                      const int* __restrict__ nLeaf, float* __restrict__ partial,
                      int* __restrict__ ctr, float* __restrict__ scal,
                      int n, int mode, int nBlocks) {
    __shared__ int   sOff[64], sN[64];
    __shared__ float sBase[64];
    __shared__ int   wSo[16], wSn[16], wSt[16];
    __shared__ float wVal[16];
    __shared__ int   sNB;
    __shared__ int   isLast;
    __shared__ float lp[1024];
    __shared__ int   cSn[24], cSt[24];
    __shared__ float cVal[24];

    int j = blockIdx.x, lane = threadIdx.x;
    int NL = *nLeaf;
    if (j < NL) {
        if (lane == 0) {
            int coff = leafOff[j] + 1, cn = leafN[j];
            int sp = 0, cnt = 0;
            for (;;) {
                if (cn <= 128) {
                    sOff[cnt] = coff; sN[cnt] = cn; cnt++;
                    bool fin = false;
                    for (;;) {
                        if (sp == 0) { fin = true; break; }
                        if (wSt[sp - 1] == 0) {
                            wSt[sp - 1] = 1;
                            int n2 = wSn[sp - 1] / 2; n2 -= (n2 & 7);
                            coff = wSo[sp - 1] + n2; cn = wSn[sp - 1] - n2;
                            break;
                        } else sp--;
                    }
                    if (fin) break;
                } else {
                    wSo[sp] = coff; wSn[sp] = cn; wSt[sp] = 0; sp++;
                    int n2 = cn / 2; n2 -= (n2 & 7);
                    cn = n2;
                }
            }
            sNB = cnt;
        }
        __syncthreads();
        int NB = sNB;
        if (lane < NB) sBase[lane] = pw_base(a + sOff[lane], b + sOff[lane], sN[lane]);
        __syncthreads();
        if (lane == 0) {
            int sp = 0, cn = leafN[j], c2 = 0;
            float res;
            for (;;) {
                if (cn <= 128) {
                    float val = sBase[c2++];
                    bool done = false;
                    for (;;) {
                        if (sp == 0) { res = val; done = true; break; }
                        if (wSt[sp - 1] == 0) {
                            wSt[sp - 1] = 1; wVal[sp - 1] = val;
                            int n2 = wSn[sp - 1] / 2; n2 -= (n2 & 7);
                            cn = wSn[sp - 1] - n2;
                            break;
                        } else { val = __fadd_rn(wVal[sp - 1], val); sp--; }
                    }
                    if (done) break;
                } else {
                    wSn[sp] = cn; wSt[sp] = 0; sp++;
                    int n2 = cn / 2; n2 -= (n2 & 7);
                    cn = n2;
                }
            }
            partial[j] = res;
        }
    }
    __threadfence();
    if (lane == 0) isLast = (atomicAdd(ctr, 1) == nBlocks - 1) ? 1 : 0;
    __syncthreads();
    if (!isLast) return;
    __threadfence();
    for (int k = lane; k < NL; k += 64) lp[k] = partial[k];
    __syncthreads();
    if (lane != 0) return;
    int cnt = 0;
    int sp = 0, cn = n;
    float res;
    for (;;) {
        if (cn <= LEAF_T) {
            float val = lp[cnt++];
            bool ret = false;
            for (;;) {
                if (sp == 0) { res = val; ret = true; break; }
                if (cSt[sp - 1] == 0) {
                    cSt[sp - 1] = 1; cVal[sp - 1] = val;
                    int n2 = cSn[sp - 1] / 2; n2 -= (n2 & 7);
                    cn = cSn[sp - 1] - n2;
                    break;
                } else { val = __fadd_rn(cVal[sp - 1], val); sp--; }
            }
            if (ret) break;
        } else {
            cSn[sp] = cn; cSt[sp] = 0; sp++;
            int n2 = cn / 2; n2 -= (n2 & 7);
            cn = n2;
        }
    }
    res = __fadd_rn(__fmul_rn(a[0], b[0]), res);   // first-element init
    if (mode == 0) {
        scal[S_RS] = res; scal[S_DONE] = 0.f; scal[S_DONE2] = 0.f;
    } else if (mode == 1) {
        scal[S_DONE] = scal[S_DONE2];  // done_old for this iteration
        scal[S_ALPHA] = __fdiv_rn(scal[S_RS], __fadd_rn(res, (float)1e-12));
    } else {
        float rs1 = res;
        scal[S_BETA] = __fdiv_rn(rs1, __fadd_rn(scal[S_RS], (float)1e-12));
        float dn = scal[S_DONE];
        if (dn == 0.f) scal[S_RS] = rs1;
        scal[S_DONE2] = (dn != 0.f || __fsqrt_rn(rs1) <= (float)1e-4) ? 1.f : 0.f;
    }
    *ctr = 0;
}

// ---------- CSR build (stable in edge order) ----------

__global__ void k_edge_pre(const int* __restrict__ dst, const int* __restrict__ src,
                           const float* __restrict__ ea, float* __restrict__ inv,
                           int* __restrict__ dstCnt, int* __restrict__ srcCnt, int E) {
    int e = blockIdx.x * blockDim.x + threadIdx.x;
    if (e >= E) return;
    float dx = fmaxf(ea[2 * e], 1e-6f);
    inv[e] = __fdiv_rn(1.f, dx);
    atomicAdd(&dstCnt[dst[e]], 1);
    atomicAdd(&srcCnt[src[e]], 1);
}

__global__ void k_scan1(const int* __restrict__ cnt, int* __restrict__ incl,
                        int* __restrict__ bsums, int N) {
    __shared__ int sm[512];
    int i = blockIdx.x * 512 + threadIdx.x;
    sm[threadIdx.x] = (i < N) ? cnt[i] : 0;
    __syncthreads();
    for (int off = 1; off < 512; off <<= 1) {
        int t = (threadIdx.x >= off) ? sm[threadIdx.x - off] : 0;
        __syncthreads();
        sm[threadIdx.x] += t;
        __syncthreads();
    }
    if (i < N) incl[i] = sm[threadIdx.x];
    if (threadIdx.x == 511) bsums[blockIdx.x] = sm[511];
}

__global__ void k_scan2(int* __restrict__ bsums, int nb) {
    __shared__ int sm[512];
    sm[threadIdx.x] = (threadIdx.x < nb) ? bsums[threadIdx.x] : 0;
    __syncthreads();
    for (int off = 1; off < 512; off <<= 1) {
        int t = (threadIdx.x >= off) ? sm[threadIdx.x - off] : 0;
        __syncthreads();
        sm[threadIdx.x] += t;
        __syncthreads();
    }
    if (threadIdx.x < nb) bsums[threadIdx.x] = sm[threadIdx.x];
}

__global__ void k_scan3(int* __restrict__ off, const int* __restrict__ bsums,
                        const int* __restrict__ cnt, int N, int E) {
    int i = blockIdx.x * 512 + threadIdx.x;
    if (i < N) {
        int add = (blockIdx.x > 0) ? bsums[blockIdx.x - 1] : 0;
        off[i] = off[i] + add - cnt[i];  // exclusive
    }
    if (i == 0) off[N] = E;
}

__global__ void k_fill(const int* __restrict__ dst, const int* __restrict__ src,
                       const int* __restrict__ dstOff, const int* __restrict__ srcOff,
                       int* __restrict__ cursD, int* __restrict__ cursS,
                       int* __restrict__ dstList, int* __restrict__ srcList, int E) {
    int e = blockIdx.x * blockDim.x + threadIdx.x;
    if (e >= E) return;
    int d = dst[e];
    dstList[dstOff[d] + atomicAdd(&cursD[d], 1)] = e;
    int s0 = src[e];
    srcList[srcOff[s0] + atomicAdd(&cursS[s0], 1)] = e;
}

__device__ __forceinline__ void insort(int* L, int lo, int hi) {
    for (int a = lo + 1; a < hi; ++a) {
        int key = L[a]; int b = a - 1;
        while (b >= lo && L[b] > key) { L[b + 1] = L[b]; b--; }
        L[b + 1] = key;
    }
}

__global__ void k_sort(const int* __restrict__ dstOff, const int* __restrict__ srcOff,
                       int* __restrict__ dstList, int* __restrict__ srcList, int N) {
    int i = blockIdx.x * blockDim.x + threadIdx.x;
    if (i >= N) return;
    insort(dstList, dstOff[i], dstOff[i + 1]);
    insort(srcList, srcOff[i], srcOff[i + 1]);
}

// ---------- physics kernels (row-per-thread, batched indirection) ----------

// slope_n (sequential, edge order); b = u - (dt*g)*slope_n -> r ; y = u*b
__global__ void k_slope_b(const float* __restrict__ u, const float* __restrict__ ea,
                          const int* __restrict__ dstOff, const int* __restrict__ dstList,
                          float* __restrict__ r, float* __restrict__ y,
                          const float* __restrict__ dtp, const float* __restrict__ gp,
                          int N) {
    int i = blockIdx.x * blockDim.x + threadIdx.x;
    if (i >= N) return;
    float dtg = __fmul_rn(dt_eff_of(dtp), gp[0]);
    float sn = 0.f;
    int k0 = dstOff[i], k1 = dstOff[i + 1];
    for (int kb = k0; kb < k1; kb += 8) {
        int eb[8]; float ax[8], ay[8];
        #pragma unroll
        for (int j = 0; j < 8; ++j) { int kk = kb + j; eb[j] = dstList[kk < k1 ? kk : (k1 - 1)]; }
        #pragma unroll
        for (int j = 0; j < 8; ++j) { ax[j] = ea[2 * eb[j]]; ay[j] = ea[2 * eb[j] + 1]; }
        #pragma unroll
        for (int j = 0; j < 8; ++j) {
            if (kb + j < k1)
                sn = __fadd_rn(sn, __fdiv_rn(ay[j], fmaxf(ax[j], 1e-6f)));
        }
    }
    const float4* ur = (const float4*)(u + (size_t)i * F);
    float4 ua = ur[0], ub = ur[1];
    float4 ba, bb, yya, yyb;
    ba.x = __fsub_rn(ua.x, __fmul_rn(dtg, sn)); yya.x = __fmul_rn(ua.x, ba.x);
    ba.y = __fsub_rn(ua.y, __fmul_rn(dtg, sn)); yya.y = __fmul_rn(ua.y, ba.y);
    ba.z = __fsub_rn(ua.z, __fmul_rn(dtg, sn)); yya.z = __fmul_rn(ua.z, ba.z);
    ba.w = __fsub_rn(ua.w, __fmul_rn(dtg, sn)); yya.w = __fmul_rn(ua.w, ba.w);
    bb.x = __fsub_rn(ub.x, __fmul_rn(dtg, sn)); yyb.x = __fmul_rn(ub.x, bb.x);
    bb.y = __fsub_rn(ub.y, __fmul_rn(dtg, sn)); yyb.y = __fmul_rn(ub.y, bb.y);
    bb.z = __fsub_rn(ub.z, __fmul_rn(dtg, sn)); yyb.z = __fmul_rn(ub.z, bb.z);
    bb.w = __fsub_rn(ub.w, __fmul_rn(dtg, sn)); yyb.w = __fmul_rn(ub.w, bb.w);
    ((float4*)(r + (size_t)i * F))[0] = ba;
    ((float4*)(r + (size_t)i * F))[1] = bb;
    ((float4*)(y + (size_t)i * F))[0] = yya;
    ((float4*)(y + (size_t)i * F))[1] = yyb;
}

// D1_T via y (= u*input), then out = base + dt*acc. Row-per-thread.
__global__ void k_d1tz(const int* __restrict__ dst, const int* __restrict__ dstOff,
                       const int* __restrict__ dstList, const int* __restrict__ srcOff,
                       const int* __restrict__ srcList, const float* __restrict__ inv,
                       const float* __restrict__ y, const float* __restrict__ base,
                       float* __restrict__ out, const float* __restrict__ dtp, int N) {
    int i = blockIdx.x * blockDim.x + threadIdx.x;
    if (i >= N) return;
    const float4* yr = (const float4*)(y + (size_t)i * F);
    float4 uya = yr[0], uyb = yr[1];
    float a0 = 0.f, a1 = 0.f, a2 = 0.f, a3 = 0.f, a4 = 0.f, a5 = 0.f, a6 = 0.f, a7 = 0.f;
    // dst pass: acc_f += uy_f * inv[e], edge order
    int k0 = dstOff[i], k1 = dstOff[i + 1];
    for (int kb = k0; kb < k1; kb += 8) {
        int eb[8]; float ivb[8];
        #pragma unroll
        for (int j = 0; j < 8; ++j) { int kk = kb + j; eb[j] = dstList[kk < k1 ? kk : (k1 - 1)]; }
        #pragma unroll
        for (int j = 0; j < 8; ++j) ivb[j] = inv[eb[j]];
        #pragma unroll
        for (int j = 0; j < 8; ++j) {
            if (kb + j < k1) {
                float iv = ivb[j];
                a0 = __fadd_rn(a0, __fmul_rn(uya.x, iv));
                a1 = __fadd_rn(a1, __fmul_rn(uya.y, iv));
                a2 = __fadd_rn(a2, __fmul_rn(uya.z, iv));
                a3 = __fadd_rn(a3, __fmul_rn(uya.w, iv));
                a4 = __fadd_rn(a4, __fmul_rn(uyb.x, iv));
                a5 = __fadd_rn(a5, __fmul_rn(uyb.y, iv));
                a6 = __fadd_rn(a6, __fmul_rn(uyb.z, iv));
                a7 = __fadd_rn(a7, __fmul_rn(uyb.w, iv));
            }
        }
    }
    // src pass: acc_f += -(y[dst[e]][f] * inv[e]), edge order
    k0 = srcOff[i]; k1 = srcOff[i + 1];
    for (int kb = k0; kb < k1; kb += 8) {
        int eb[8]; float ivb[8]; int db[8]; float4 qa[8], qb[8];
        #pragma unroll
        for (int j = 0; j < 8; ++j) { int kk = kb + j; eb[j] = srcList[kk < k1 ? kk : (k1 - 1)]; }
        #pragma unroll
        for (int j = 0; j < 8; ++j) { ivb[j] = inv[eb[j]]; db[j] = dst[eb[j]]; }
        #pragma unroll
        for (int j = 0; j < 8; ++j) {
            const float4* q = (const float4*)(y + (size_t)db[j] * F);
            qa[j] = q[0]; qb[j] = q[1];
        }
        #pragma unroll
        for (int j = 0; j < 8; ++j) {
            if (kb + j < k1) {
                float iv = ivb[j];
                a0 = __fadd_rn(a0, -__fmul_rn(qa[j].x, iv));
                a1 = __fadd_rn(a1, -__fmul_rn(qa[j].y, iv));
                a2 = __fadd_rn(a2, -__fmul_rn(qa[j].z, iv));
                a3 = __fadd_rn(a3, -__fmul_rn(qa[j].w, iv));
                a4 = __fadd_rn(a4, -__fmul_rn(qb[j].x, iv));
                a5 = __fadd_rn(a5, -__fmul_rn(qb[j].y, iv));
                a6 = __fadd_rn(a6, -__fmul_rn(qb[j].z, iv));
                a7 = __fadd_rn(a7, -__fmul_rn(qb[j].w, iv));
            }
        }
    }
    float dt = dt_eff_of(dtp);
    const float4* br = (const float4*)(base + (size_t)i * F);
    float4 ba = br[0], bb = br[1], oa, ob;
    oa.x = __fadd_rn(ba.x, __fmul_rn(dt, a0));
    oa.y = __fadd_rn(ba.y, __fmul_rn(dt, a1));
    oa.z = __fadd_rn(ba.z, __fmul_rn(dt, a2));
    oa.w = __fadd_rn(ba.w, __fmul_rn(dt, a3));
    ob.x = __fadd_rn(bb.x, __fmul_rn(dt, a4));
    ob.y = __fadd_rn(bb.y, __fmul_rn(dt, a5));
    ob.z = __fadd_rn(bb.z, __fmul_rn(dt, a6));
    ob.w = __fadd_rn(bb.w, __fmul_rn(dt, a7));
    ((float4*)(out + (size_t)i * F))[0] = oa;
    ((float4*)(out + (size_t)i * F))[1] = ob;
}

// r = p copy ; x = 0  (float4)
__global__ void k_init(const float4* __restrict__ p4, float4* __restrict__ r4,
                       float4* __restrict__ x4, int n4) {
    int i = blockIdx.x * blockDim.x + threadIdx.x;
    if (i >= n4) return;
    r4[i] = p4[i];
    x4[i] = make_float4(0.f, 0.f, 0.f, 0.f);
}

// D1(p) fused with w = p + dt*(u*t) and y = u*w. Row-per-thread.
__global__ void k_d1w(const int* __restrict__ src, const int* __restrict__ dstOff,
                      const int* __restrict__ dstList, const float* __restrict__ inv,
                      const float* __restrict__ pv, const float* __restrict__ u,
                      float* __restrict__ w, float* __restrict__ y,
                      const float* __restrict__ dtp, int N) {
    int i = blockIdx.x * blockDim.x + threadIdx.x;
    if (i >= N) return;
    const float4* pr = (const float4*)(pv + (size_t)i * F);
    float4 pa = pr[0], pb = pr[1];
    float a0 = 0.f, a1 = 0.f, a2 = 0.f, a3 = 0.f, a4 = 0.f, a5 = 0.f, a6 = 0.f, a7 = 0.f;
    int k0 = dstOff[i], k1 = dstOff[i + 1];
    for (int kb = k0; kb < k1; kb += 8) {
        int eb[8]; float ivb[8]; int sb[8]; float4 qa[8], qb[8];
        #pragma unroll
        for (int j = 0; j < 8; ++j) { int kk = kb + j; eb[j] = dstList[kk < k1 ? kk : (k1 - 1)]; }
        #pragma unroll
        for (int j = 0; j < 8; ++j) { ivb[j] = inv[eb[j]]; sb[j] = src[eb[j]]; }
        #pragma unroll
        for (int j = 0; j < 8; ++j) {
            const float4* q = (const float4*)(pv + (size_t)sb[j] * F);
            qa[j] = q[0]; qb[j] = q[1];
        }
        #pragma unroll
        for (int j = 0; j < 8; ++j) {
            if (kb + j < k1) {
                float iv = ivb[j];
                a0 = __fadd_rn(a0, __fmul_rn(__fsub_rn(pa.x, qa[j].x), iv));
                a1 = __fadd_rn(a1, __fmul_rn(__fsub_rn(pa.y, qa[j].y), iv));
                a2 = __fadd_rn(a2, __fmul_rn(__fsub_rn(pa.z, qa[j].z), iv));
                a3 = __fadd_rn(a3, __fmul_rn(__fsub_rn(pa.w, qa[j].w), iv));
                a4 = __fadd_rn(a4, __fmul_rn(__fsub_rn(pb.x, qb[j].x), iv));
                a5 = __fadd_rn(a5, __fmul_rn(__fsub_rn(pb.y, qb[j].y), iv));
                a6 = __fadd_rn(a6, __fmul_rn(__fsub_rn(pb.z, qb[j].z), iv));
                a7 = __fadd_rn(a7, __fmul_rn(__fsub_rn(pb.w, qb[j].w), iv));
            }
        }
    }
    float dt = dt_eff_of(dtp);
    const float4* ur = (const float4*)(u + (size_t)i * F);
    float4 ua = ur[0], ub = ur[1];
    float4 wa, wb, yya, yyb;
    wa.x = __fadd_rn(pa.x, __fmul_rn(dt, __fmul_rn(ua.x, a0))); yya.x = __fmul_rn(ua.x, wa.x);
    wa.y = __fadd_rn(pa.y, __fmul_rn(dt, __fmul_rn(ua.y, a1))); yya.y = __fmul_rn(ua.y, wa.y);
    wa.z = __fadd_rn(pa.z, __fmul_rn(dt, __fmul_rn(ua.z, a2))); yya.z = __fmul_rn(ua.z, wa.z);
    wa.w = __fadd_rn(pa.w, __fmul_rn(dt, __fmul_rn(ua.w, a3))); yya.w = __fmul_rn(ua.w, wa.w);
    wb.x = __fadd_rn(pb.x, __fmul_rn(dt, __fmul_rn(ub.x, a4))); yyb.x = __fmul_rn(ub.x, wb.x);
    wb.y = __fadd_rn(pb.y, __fmul_rn(dt, __fmul_rn(ub.y, a5))); yyb.y = __fmul_rn(ub.y, wb.y);
    wb.z = __fadd_rn(pb.z, __fmul_rn(dt, __fmul_rn(ub.z, a6))); yyb.z = __fmul_rn(ub.z, wb.z);
    wb.w = __fadd_rn(pb.w, __fmul_rn(dt, __fmul_rn(ub.w, a7))); yyb.w = __fmul_rn(ub.w, wb.w);
    ((float4*)(w + (size_t)i * F))[0] = wa;
    ((float4*)(w + (size_t)i * F))[1] = wb;
    ((float4*)(y + (size_t)i * F))[0] = yya;
    ((float4*)(y + (size_t)i * F))[1] = yyb;
}

// x += alpha*p ; r -= alpha*z   (guarded by done_old)  float4
__global__ void k_xr(float4* __restrict__ x4, float4* __restrict__ r4,
                     const float4* __restrict__ p4, const float4* __restrict__ z4,
                     const float* __restrict__ scal, int n4) {
    int i = blockIdx.x * blockDim.x + threadIdx.x;
    if (i >= n4) return;
    if (scal[S_DONE] != 0.f) return;
    float al = scal[S_ALPHA];
    float4 xv = x4[i], pv = p4[i], rv = r4[i], zv = z4[i];
    xv.x = __fadd_rn(xv.x, __fmul_rn(al, pv.x));
    xv.y = __fadd_rn(xv.y, __fmul_rn(al, pv.y));
    xv.z = __fadd_rn(xv.z, __fmul_rn(al, pv.z));
    xv.w = __fadd_rn(xv.w, __fmul_rn(al, pv.w));
    rv.x = __fsub_rn(rv.x, __fmul_rn(al, zv.x));
    rv.y = __fsub_rn(rv.y, __fmul_rn(al, zv.y));
    rv.z = __fsub_rn(rv.z, __fmul_rn(al, zv.z));
    rv.w = __fsub_rn(rv.w, __fmul_rn(al, zv.w));
    x4[i] = xv;
    r4[i] = rv;
}

// p = r + beta*p   (guarded by done_old)  float4
__global__ void k_p(float4* __restrict__ p4, const float4* __restrict__ r4,
                    const float* __restrict__ scal, int n4) {
    int i = blockIdx.x * blockDim.x + threadIdx.x;
    if (i >= n4) return;
    if (scal[S_DONE] != 0.f) return;
    float be = scal[S_BETA];
    float4 pv = p4[i], rv = r4[i];
    pv.x = __fadd_rn(rv.x, __fmul_rn(be, pv.x));
    pv.y = __fadd_rn(rv.y, __fmul_rn(be, pv.y));
    pv.z = __fadd_rn(rv.z, __fmul_rn(be, pv.z));
    pv.w = __fadd_rn(rv.w, __fmul_rn(be, pv.w));
    p4[i] = pv;
}

// host-side replica of the leaf count (same recursion as k_build_leaves)
static int host_count_leaves(int n) {
    int st[64]; int sp = 0; st[sp++] = n; int cnt = 0;
    while (sp > 0) {
        int nn = st[--sp];
        if (nn <= LEAF_T) { cnt++; continue; }
        int n2 = nn / 2; n2 -= (n2 & 7);
        st[sp++] = nn - n2;
        st[sp++] = n2;
    }
    return cnt;
}

extern "C" void kernel_launch(void* const* d_in, const int* in_sizes, int n_in,
                              void* d_out, int out_size, void* d_ws, size_t ws_size,
                              hipStream_t stream) {
    const float* u   = (const float*)d_in[0];
    const int*   ei  = (const int*)d_in[1];
    const float* ea  = (const float*)d_in[2];
    const float* dtp = (const float*)d_in[3];
    const float* gp  = (const float*)d_in[4];

    const int NF = in_sizes[0];        // 1,600,000
    const int N  = NF / F;             // 200,000
    const int E  = in_sizes[2] / 2;    // 3,200,000
    const int* srcp = ei;
    const int* dstp = ei + E;

    char* wp = (char*)d_ws;
    float* scal    = (float*)wp; wp += 64 * 4;
    float* r       = (float*)wp; wp += (size_t)NF * 4;
    float* p       = (float*)wp; wp += (size_t)NF * 4;
    float* t       = (float*)wp; wp += (size_t)NF * 4;   // z
    float* w       = (float*)wp; wp += (size_t)NF * 4;
    float* y       = (float*)wp; wp += (size_t)NF * 4;   // u*w / u*b
    float* inv     = (float*)wp; wp += (size_t)E * 4;
    int*   dstList = (int*)wp;   wp += (size_t)E * 4;
    int*   srcList = (int*)wp;   wp += (size_t)E * 4;
    int*   dstOff  = (int*)wp;   wp += (size_t)(N + 1) * 4;
    int*   srcOff  = (int*)wp;   wp += (size_t)(N + 1) * 4;
    int*   dstCnt  = (int*)wp;   wp += (size_t)N * 4;
    int*   srcCnt  = (int*)wp;   wp += (size_t)N * 4;
    int*   cursD   = (int*)wp;   wp += (size_t)N * 4;
    int*   cursS   = (int*)wp;   wp += (size_t)N * 4;
    int*   bsD     = (int*)wp;   wp += 512 * 4;
    int*   bsS     = (int*)wp;   wp += 512 * 4;
    int*   leafOff = (int*)wp;   wp += 2048 * 4;
    int*   leafN   = (int*)wp;   wp += 2048 * 4;
    int*   nLeaf   = (int*)wp;   wp += 64;
    float* partial = (float*)wp; wp += 2048 * 4;
    float* x = (float*)d_out;
    int*   ctr = (int*)(scal + 32);

    hipMemsetAsync(scal, 0, 64 * 4, stream);
    hipMemsetAsync(dstCnt, 0, (size_t)N * 4, stream);
    hipMemsetAsync(srcCnt, 0, (size_t)N * 4, stream);
    hipMemsetAsync(cursD, 0, (size_t)N * 4, stream);
    hipMemsetAsync(cursS, 0, (size_t)N * 4, stream);

    const int bn = 256;
    const int gN  = (N + bn - 1) / bn;
    const int gE  = (E + bn - 1) / bn;
    const int nb  = (N + 511) / 512;
    const int n4  = NF / 4;
    const int g4  = (n4 + bn - 1) / bn;
    const int NL  = host_count_leaves(NF - 1);   // exact k_dot grid

    // ---- CSR build (stable by edge id) ----
    k_edge_pre<<<gE, bn, 0, stream>>>(dstp, srcp, ea, inv, dstCnt, srcCnt, E);
    k_scan1<<<nb, 512, 0, stream>>>(dstCnt, dstOff, bsD, N);
    k_scan2<<<1, 512, 0, stream>>>(bsD, nb);
    k_scan3<<<nb, 512, 0, stream>>>(dstOff, bsD, dstCnt, N, E);
    k_scan1<<<nb, 512, 0, stream>>>(srcCnt, srcOff, bsS, N);
    k_scan2<<<1, 512, 0, stream>>>(bsS, nb);
    k_scan3<<<nb, 512, 0, stream>>>(srcOff, bsS, srcCnt, N, E);
    k_fill<<<gE, bn, 0, stream>>>(dstp, srcp, dstOff, srcOff, cursD, cursS,
                                  dstList, srcList, E);
    k_sort<<<gN, bn, 0, stream>>>(dstOff, srcOff, dstList, srcList, N);
    k_build_leaves<<<1, 64, 0, stream>>>(NF - 1, leafOff, leafN, nLeaf);

    // ---- setup: b->r, y=u*b ; p = b + dt*D1T(y) ; r=p, x=0 ; rs0 = p.p ----
    k_slope_b<<<gN, bn, 0, stream>>>(u, ea, dstOff, dstList, r, y, dtp, gp, N);
    k_d1tz<<<gN, bn, 0, stream>>>(dstp, dstOff, dstList, srcOff, srcList, inv,
                                  y, r, p, dtp, N);
    k_init<<<g4, bn, 0, stream>>>((const float4*)p, (float4*)r, (float4*)x, n4);
    k_dot<<<NL, 64, 0, stream>>>(p, p, leafOff, leafN, nLeaf, partial, ctr,
                                 scal, NF - 1, 0, NL);

    // ---- CG loop ----
    for (int it = 0; it < CG_ITERS; ++it) {
        k_d1w<<<gN, bn, 0, stream>>>(srcp, dstOff, dstList, inv, p, u, w, y,
                                     dtp, N);
        k_d1tz<<<gN, bn, 0, stream>>>(dstp, dstOff, dstList, srcOff, srcList,
                                      inv, y, w, t, dtp, N);
        k_dot<<<NL, 64, 0, stream>>>(p, t, leafOff, leafN, nLeaf, partial,
                                     ctr, scal, NF - 1, 1, NL);
        k_xr<<<g4, bn, 0, stream>>>((float4*)x, (float4*)r, (const float4*)p,
                                    (const float4*)t, scal, n4);
        k_dot<<<NL, 64, 0, stream>>>(r, r, leafOff, leafN, nLeaf, partial,
                                     ctr, scal, NF - 1, 2, NL);
        k_p<<<g4, bn, 0, stream>>>((float4*)p, (const float4*)r, scal, n4);
    }
}